// Round 9
// baseline (221.083 us; speedup 1.0000x reference)
//
#include <hip/hip_runtime.h>
#include <stdint.h>

typedef __bf16 bf16x8 __attribute__((ext_vector_type(8)));
typedef float  f32x4  __attribute__((ext_vector_type(4)));

#define ATTN_SCALE 2.7621359e-3f   // 1/(sqrt(128)*sqrt(1024))

__device__ __forceinline__ unsigned short f2bf(float f) {
  union { float f; uint32_t u; } v; v.f = f;
  uint32_t u = v.u;
  uint32_t r = (u + 0x7FFFu + ((u >> 16) & 1u)) >> 16;   // RNE
  return (unsigned short)r;
}

__device__ __forceinline__ void load_lds16(const unsigned short* g, unsigned short* l) {
  __builtin_amdgcn_global_load_lds(
      (const __attribute__((address_space(1))) void*)g,
      (__attribute__((address_space(3))) void*)l, 16, 0, 0);
}

__device__ __forceinline__ f32x4 mfma16(bf16x8 a, bf16x8 b, f32x4 c) {
  return __builtin_amdgcn_mfma_f32_16x16x32_bf16(a, b, c, 0, 0, 0);
}

__device__ __forceinline__ bf16x8 ones_bf16() {
  union { unsigned short u[8]; bf16x8 v; } c;
#pragma unroll
  for (int j = 0; j < 8; ++j) c.u[j] = 0x3F80;   // bf16 1.0
  return c.v;
}

// ---------------------------------------------------------------- QKV projection GEMM
// [frozen from round 8 - passed] 3-pass structure (768 blocks = 3/CU, 12 KB
// LDS) with weight conversion fused in: B reg-staged from f32 W via f2bf RNE
// -> ds_write_b128 (bit-identical to the old cvtw + global_load_lds path).
__global__ __launch_bounds__(256, 3) void k_proj(
    const float* __restrict__ X,             // [16384][1024] f32
    const float* __restrict__ Wq,            // [128][1024] f32
    const float* __restrict__ Wk,
    const float* __restrict__ Wv,
    unsigned short* __restrict__ Qb,         // [16384][128]
    unsigned short* __restrict__ Kb,         // [16384][128]
    unsigned short* __restrict__ Vt)         // [4][128][4096]
{
  __shared__ __align__(16) unsigned short sm[2048 + 4096];   // As[64][32] | Bs[128][32], 12 KB
  unsigned short* As = sm;
  unsigned short* Bs = sm + 2048;
  const int t = threadIdx.x;
  const int mtile = blockIdx.x;          // 0..255 (64 rows each)
  const int nt = blockIdx.y;             // 0..2  (Q, K, V weight)
  const int w = t >> 6, lane = t & 63, quad = lane >> 4, l15 = lane & 15;
  const int wm = w & 1, wn = w >> 1;

  const float* Wsel = (nt == 0) ? Wq : (nt == 1) ? Wk : Wv;

  const float* ag0 = X + (size_t)(mtile * 64 + (t >> 2)) * 1024 + (t & 3) * 8;
  const float* bg0 = Wsel + (size_t)(t >> 2) * 1024 + (t & 3) * 8;
  unsigned short* aw = &As[t * 8];       // == row(t>>2)*32 + (t&3)*8, linear in t
  unsigned short* bw = &Bs[t * 8];

  f32x4 acc[2][4] = {};

  // prologue: kt=0 A and B f32 loads in flight
  float4 a0 = *(const float4*)(ag0);
  float4 a1 = *(const float4*)(ag0 + 4);
  float4 b0 = *(const float4*)(bg0);
  float4 b1 = *(const float4*)(bg0 + 4);
  float4 b2 = *(const float4*)(bg0 + 65536);       // row +64
  float4 b3 = *(const float4*)(bg0 + 65536 + 4);

  for (int kt = 0; kt < 32; ++kt) {
    __syncthreads();                       // prior MFMA LDS reads done
    {
      union { unsigned short u[8]; uint4 v; } pa;
      pa.u[0] = f2bf(a0.x); pa.u[1] = f2bf(a0.y);
      pa.u[2] = f2bf(a0.z); pa.u[3] = f2bf(a0.w);
      pa.u[4] = f2bf(a1.x); pa.u[5] = f2bf(a1.y);
      pa.u[6] = f2bf(a1.z); pa.u[7] = f2bf(a1.w);
      *(uint4*)aw = pa.v;                  // ds_write_b128 (A row t>>2)
      union { unsigned short u[8]; uint4 v; } pb;
      pb.u[0] = f2bf(b0.x); pb.u[1] = f2bf(b0.y);
      pb.u[2] = f2bf(b0.z); pb.u[3] = f2bf(b0.w);
      pb.u[4] = f2bf(b1.x); pb.u[5] = f2bf(b1.y);
      pb.u[6] = f2bf(b1.z); pb.u[7] = f2bf(b1.w);
      *(uint4*)bw = pb.v;                  // B row t>>2
      pb.u[0] = f2bf(b2.x); pb.u[1] = f2bf(b2.y);
      pb.u[2] = f2bf(b2.z); pb.u[3] = f2bf(b2.w);
      pb.u[4] = f2bf(b3.x); pb.u[5] = f2bf(b3.y);
      pb.u[6] = f2bf(b3.z); pb.u[7] = f2bf(b3.w);
      *(uint4*)(bw + 2048) = pb.v;         // B row 64+(t>>2)
    }
    if (kt < 31) {                         // issue next-kt loads; covered by sync+MFMA
      a0 = *(const float4*)(ag0 + (kt + 1) * 32);
      a1 = *(const float4*)(ag0 + (kt + 1) * 32 + 4);
      b0 = *(const float4*)(bg0 + (kt + 1) * 32);
      b1 = *(const float4*)(bg0 + (kt + 1) * 32 + 4);
      b2 = *(const float4*)(bg0 + (kt + 1) * 32 + 65536);
      b3 = *(const float4*)(bg0 + (kt + 1) * 32 + 65536 + 4);
    }
    __syncthreads();                       // drains A/B ds_writes

    bf16x8 af[2], bfr[4];
#pragma unroll
    for (int i = 0; i < 2; ++i)
      af[i] = *(const bf16x8*)&As[(wm * 32 + i * 16 + l15) * 32 + quad * 8];
#pragma unroll
    for (int j = 0; j < 4; ++j)
      bfr[j] = *(const bf16x8*)&Bs[(wn * 64 + j * 16 + l15) * 32 + quad * 8];
#pragma unroll
    for (int i = 0; i < 2; ++i)
#pragma unroll
      for (int j = 0; j < 4; ++j)
        acc[i][j] = mfma16(af[i], bfr[j], acc[i][j]);
  }

  if (nt != 2) {
    const int m0 = mtile * 64 + wm * 32;
#pragma unroll
    for (int i = 0; i < 2; ++i)
#pragma unroll
      for (int j = 0; j < 4; ++j)
#pragma unroll
        for (int r = 0; r < 4; ++r) {
          int m = m0 + i * 16 + quad * 4 + r;
          int n = wn * 64 + j * 16 + l15;
          float v = acc[i][j][r];
          if (nt == 0) Qb[(size_t)m * 128 + n] = f2bf(v * ATTN_SCALE);
          else         Kb[(size_t)m * 128 + n] = f2bf(v);
        }
  } else {
    // transpose through LDS -> coalesced Vt writes
    // NOTE: jj loop MUST be fully unrolled (j indexes the acc register array;
    // runtime index demotes acc to scratch -> massive spill traffic).
    float* Ts = (float*)sm;                   // [64 m][17] f32 (4352 B)
    const int bb = mtile >> 6;
    const int s0 = (mtile & 63) * 64;
#pragma unroll
    for (int jj = 0; jj < 8; ++jj) {
      __syncthreads();
      if (wn == (jj >> 2)) {
        const int j = jj & 3;
#pragma unroll
        for (int i = 0; i < 2; ++i)
#pragma unroll
          for (int r = 0; r < 4; ++r)
            Ts[(wm * 32 + i * 16 + quad * 4 + r) * 17 + l15] = acc[i][j][r];
      }
      __syncthreads();
      int n2 = jj * 16 + (t >> 4);            // d index within this 16-col chunk
      int m2 = (t & 15) * 4;                  // 4 seq rows per thread
      union { unsigned short u[4]; uint2 v; } pk;
#pragma unroll
      for (int e = 0; e < 4; ++e) pk.u[e] = f2bf(Ts[(m2 + e) * 17 + (t >> 4)]);
      *(uint2*)&Vt[((size_t)(bb * 128 + n2)) * 4096 + s0 + m2] = pk.v;
    }
  }
}

// ---------------------------------------------------------------- flash attention
// v7: LDS-traffic diet. Accounting across rounds 2-8 (all schedule knobs null,
// all pipes <31%) pins flash at the LDS-datapath roofline: 112 KB/block-iter
// (stage 32 + K-reads 32 + V-reads 32 + P 16) x 16384 block-iters = 1.84 GB
// ~= 35-55 us at measured LDS rates. This version removes the V path from LDS
// entirely (-43%): PV B-fragments are loaded straight from L2-resident Vt into
// registers (lane(l15,quad) reads 16 B at d=dt*16+l15, keys=(p*4+quad)*8; the
// 4 quads of a d-row consume 64 consecutive B, p=0/1 waves the two halves of
// each 128 B line -> full line utilization, r3's XCD affinity keeps it L2-hit).
// With V out of LDS the beta barrier has no job left (P is wave-private), so
// K is double-buffered and the loop runs ONE barrier + ONE vmcnt per iter:
//   alpha: vmcnt(0)+bar  (K[kt] resident; all QK(i-1) reads done -> buf free)
//   issue K[kt+1] -> buf[nxt] | issue V frags -> regs (covered by QK+softmax)
//   QK | softmax | P write | lgkm(0) | PV from regs
// Numerics bit-identical (same __expf, f2bf, MFMA order). LDS 43008 B.
__global__ __launch_bounds__(256, 3) void k_flash(
    const unsigned short* __restrict__ Qb,   // [4][4096][128] bf16, pre-scaled
    const unsigned short* __restrict__ Kb,   // [4][4096][128] bf16
    const unsigned short* __restrict__ Vt,   // [4][128][4096] bf16
    float* __restrict__ Om,                  // [2][16384][128] f32 partials
    float* __restrict__ lp)                  // [2][16384] row sums
{
  __shared__ __align__(16) unsigned short smem[21504];   // 43008 B
  // K0 [0,8192) | K1 [8192,16384) | P [16384,21504)
  unsigned short* Psh = smem + 16384;    // per-wave [32 q][stride 40]
  float* Ob  = (float*)smem;             // epilogue overlay [64][128] f32 (over K bufs)
  float* lsh = (float*)(smem + 16384);   // epilogue overlay [64] f32 (over P)

  const int t = threadIdx.x;
  const int w = t >> 6, lane = t & 63, quad = lane >> 4, l15 = lane & 15;
  const int h = w & 1, p = w >> 1;
  // XCD-affine decode: xcd = bid & 7; pair (2b, 2b+1) = batch b; even XCD of
  // the pair gets keys 0..2047 (sp=0), odd 2048..4095. K/V ~1 MB per XCD L2.
  const int bid = blockIdx.x;            // 0..511
  const int b   = (bid & 7) >> 1;
  const int sp  = bid & 1;
  const int qt  = bid >> 3;              // 0..63

  const unsigned short* Qg = Qb + (size_t)(b * 4096 + qt * 64 + h * 32) * 128;
  const unsigned short* Kg = Kb + (size_t)b * 4096 * 128;
  const unsigned short* Vg = Vt + (size_t)b * 128 * 4096;

  bf16x8 qf[2][4];
#pragma unroll
  for (int mt = 0; mt < 2; ++mt)
#pragma unroll
    for (int kk = 0; kk < 4; ++kk)
      qf[mt][kk] = *(const bf16x8*)&Qg[(size_t)(mt * 16 + l15) * 128 + kk * 32 + quad * 8];

  f32x4 O[2][8] = {};
  f32x4 Ol[2] = {};

  // K staging map (chunk-XOR swizzled on the fetch side, as before):
  const unsigned short* kg0 = Kg + (size_t)(t >> 4) * 128 + (((t & 15) ^ ((t >> 5) & 7)) * 8);
  // V direct-read base: lane(l15,quad) -> d-row l15 (+dt*16), key chunk (p*4+quad)*8
  const unsigned short* vgb = Vg + (size_t)l15 * 4096 + (p * 4 + quad) * 8;

  const int kt0 = sp * 32;

  // prologue: K(kt0) -> K0
  {
    const unsigned short* kg = kg0 + (size_t)kt0 * 8192;
    unsigned short* kw = &smem[w * 512];
#pragma unroll
    for (int it = 0; it < 4; ++it)
      load_lds16(kg + it * 2048, kw + it * 2048);
  }

  for (int i = 0; i < 32; ++i) {
    const int cur = i & 1, nxt = cur ^ 1;
    const int kt = kt0 + i;
    const int ktn = (i < 31) ? (kt + 1) : kt0;   // wrap dummy on last iter
                                                 // (drained by the epilogue
                                                 // __syncthreads before overlay)

    // alpha (the ONLY barrier per iter): K[kt] resident (own loads are the
    // only outstanding vmem; V-frag loads of iter i-1 were consumed by PV).
    // Barrier also certifies all waves finished QK(i-1) -> buf[nxt] is free.
    asm volatile("s_waitcnt vmcnt(0)" ::: "memory");
    asm volatile("s_barrier" ::: "memory");

    // issue K[ktn] -> buf[nxt] (has a full iteration to land)
    {
      const unsigned short* kg = kg0 + (size_t)ktn * 8192;
      unsigned short* kw = &smem[nxt * 8192 + w * 512];
#pragma unroll
      for (int it = 0; it < 4; ++it)
        load_lds16(kg + it * 2048, kw + it * 2048);
    }

    // issue V fragments for THIS tile straight to registers (L2-hit; the
    // compiler hoists these loads here, PV consumes them ~450 cyc later)
    bf16x8 vfr[8];
#pragma unroll
    for (int dt = 0; dt < 8; ++dt)
      vfr[dt] = *(const bf16x8*)&vgb[(size_t)dt * 65536 + (size_t)kt * 64];

    // S = Q K^T on K[cur] (keys paired even/odd: lane l15 holds
    // keys p*32 + 2*l15 + ntk)
    const unsigned short* Kshc = &smem[cur * 8192];
    f32x4 sc[2][2] = {};
#pragma unroll
    for (int ntk = 0; ntk < 2; ++ntk) {
      const int row = p * 32 + 2 * l15 + ntk;
#pragma unroll
      for (int kk = 0; kk < 4; ++kk) {
        bf16x8 kf = *(const bf16x8*)&Kshc[row * 128 + (((kk * 4 + quad) ^ (l15 & 7)) * 8)];
        sc[0][ntk] = mfma16(qf[0][kk], kf, sc[0][ntk]);
        sc[1][ntk] = mfma16(qf[1][kk], kf, sc[1][ntk]);
      }
    }

    // P = exp(S) (no max shift), packed pair writes (keys 2*l15, 2*l15+1)
#pragma unroll
    for (int mt = 0; mt < 2; ++mt)
#pragma unroll
      for (int r = 0; r < 4; ++r) {
        float e0 = __expf(sc[mt][0][r]);
        float e1 = __expf(sc[mt][1][r]);
        int row = mt * 16 + quad * 4 + r;
        uint32_t pk = (uint32_t)f2bf(e0) | ((uint32_t)f2bf(e1) << 16);
        *(uint32_t*)&Psh[w * 1280 + row * 40 + 2 * l15] = pk;
      }

    // P roundtrip is wave-private: no barrier, just drain own LDS ops.
    asm volatile("s_waitcnt lgkmcnt(0)" ::: "memory");

    bf16x8 pf0 = *(const bf16x8*)&Psh[w * 1280 + l15 * 40 + quad * 8];
    bf16x8 pf1 = *(const bf16x8*)&Psh[w * 1280 + (16 + l15) * 40 + quad * 8];
    const bf16x8 one = ones_bf16();
    Ol[0] = mfma16(pf0, one, Ol[0]);     // row-sums of P (free l accumulate)
    Ol[1] = mfma16(pf1, one, Ol[1]);
#pragma unroll
    for (int dt = 0; dt < 8; ++dt) {
      O[0][dt] = mfma16(pf0, vfr[dt], O[0][dt]);
      O[1][dt] = mfma16(pf1, vfr[dt], O[1][dt]);
    }
  }

  // ---- merge the two key-half partials (additive: no max state) ----
  // __syncthreads drains vmcnt(0) (wrap-dummy K prefetch lands BEFORE the
  // overlay writes below) + lgkmcnt, then barrier.
  __syncthreads();
  if (p == 1) {
#pragma unroll
    for (int mt = 0; mt < 2; ++mt)
#pragma unroll
      for (int r = 0; r < 4; ++r) {
        int row = h * 32 + mt * 16 + quad * 4 + r;
        if (l15 == 0) lsh[row] = Ol[mt][r];
#pragma unroll
        for (int dt = 0; dt < 8; ++dt)
          Ob[row * 128 + dt * 16 + l15] = O[mt][dt][r];
      }
  }
  __syncthreads();
  if (p == 0) {
    const size_t rowbase = (size_t)b * 4096 + qt * 64;
    float* Omp = Om + (size_t)sp * 2097152;
#pragma unroll
    for (int mt = 0; mt < 2; ++mt)
#pragma unroll
      for (int r = 0; r < 4; ++r) {
        int row = h * 32 + mt * 16 + quad * 4 + r;
#pragma unroll
        for (int dt = 0; dt < 8; ++dt)
          Omp[(rowbase + row) * 128 + dt * 16 + l15] =
              O[mt][dt][r] + Ob[row * 128 + dt * 16 + l15];
        if (l15 == 0)
          lp[(size_t)sp * 16384 + rowbase + row] = Ol[mt][r] + lsh[row];
      }
  }
}

// ---------------------------------------------------------------- merge key-splits
__global__ __launch_bounds__(256) void k_merge(const float* __restrict__ Om,
                                               const float* __restrict__ lp,
                                               float* __restrict__ out) {
  int i = blockIdx.x * 256 + threadIdx.x;   // float4 index, 524288 total
  int row = i >> 5;
  float inv = 1.0f / (lp[row] + lp[16384 + row]);
  float4 a = ((const float4*)Om)[i];
  float4 c = ((const float4*)Om)[524288 + i];
  float4 o;
  o.x = (a.x + c.x) * inv;
  o.y = (a.y + c.y) * inv;
  o.z = (a.z + c.z) * inv;
  o.w = (a.w + c.w) * inv;
  ((float4*)out)[i] = o;
}

// ---------------------------------------------------------------- launch
extern "C" void kernel_launch(void* const* d_in, const int* in_sizes, int n_in,
                              void* d_out, int out_size, void* d_ws, size_t ws_size,
                              hipStream_t stream) {
  const float* x  = (const float*)d_in[0];   // [4,4096,1024]
  const float* Wq = (const float*)d_in[1];   // [128,1024]
  const float* Wk = (const float*)d_in[2];
  const float* Wv = (const float*)d_in[3];
  float* out = (float*)d_out;                // [4,4096,128]

  unsigned short* ws  = (unsigned short*)d_ws;
  unsigned short* Qb  = ws;                   // 2,097,152 ush
  unsigned short* Kb  = Qb + 2097152;
  unsigned short* Vt  = Kb + 2097152;         // 2,097,152
  float* Om = (float*)(Vt + 2097152);         // 2*16384*128 f32
  float* lp = Om + 4194304;                   // 2*16384 f32

  k_proj<<<dim3(256, 3), 256, 0, stream>>>(x, Wq, Wk, Wv, Qb, Kb, Vt);
  k_flash<<<512, 256, 0, stream>>>(Qb, Kb, Vt, Om, lp);
  k_merge<<<2048, 256, 0, stream>>>(Om, lp, out);
}

// Round 10
// 218.860 us; speedup vs baseline: 1.0102x; 1.0102x over previous
//
#include <hip/hip_runtime.h>
#include <stdint.h>

typedef __bf16 bf16x8 __attribute__((ext_vector_type(8)));
typedef float  f32x4  __attribute__((ext_vector_type(4)));

#define ATTN_SCALE 2.7621359e-3f   // 1/(sqrt(128)*sqrt(1024))

__device__ __forceinline__ unsigned short f2bf(float f) {
  union { float f; uint32_t u; } v; v.f = f;
  uint32_t u = v.u;
  uint32_t r = (u + 0x7FFFu + ((u >> 16) & 1u)) >> 16;   // RNE
  return (unsigned short)r;
}

__device__ __forceinline__ void load_lds16(const unsigned short* g, unsigned short* l) {
  __builtin_amdgcn_global_load_lds(
      (const __attribute__((address_space(1))) void*)g,
      (__attribute__((address_space(3))) void*)l, 16, 0, 0);
}

__device__ __forceinline__ f32x4 mfma16(bf16x8 a, bf16x8 b, f32x4 c) {
  return __builtin_amdgcn_mfma_f32_16x16x32_bf16(a, b, c, 0, 0, 0);
}

__device__ __forceinline__ bf16x8 ones_bf16() {
  union { unsigned short u[8]; bf16x8 v; } c;
#pragma unroll
  for (int j = 0; j < 8; ++j) c.u[j] = 0x3F80;   // bf16 1.0
  return c.v;
}

// ---------------------------------------------------------------- QKV projection GEMM
// [frozen from round 8 - passed] 3-pass structure (768 blocks = 3/CU, 12 KB
// LDS) with weight conversion fused in: B reg-staged from f32 W via f2bf RNE
// -> ds_write_b128 (bit-identical to the old cvtw + global_load_lds path).
__global__ __launch_bounds__(256, 3) void k_proj(
    const float* __restrict__ X,             // [16384][1024] f32
    const float* __restrict__ Wq,            // [128][1024] f32
    const float* __restrict__ Wk,
    const float* __restrict__ Wv,
    unsigned short* __restrict__ Qb,         // [16384][128]
    unsigned short* __restrict__ Kb,         // [16384][128]
    unsigned short* __restrict__ Vt)         // [4][128][4096]
{
  __shared__ __align__(16) unsigned short sm[2048 + 4096];   // As[64][32] | Bs[128][32], 12 KB
  unsigned short* As = sm;
  unsigned short* Bs = sm + 2048;
  const int t = threadIdx.x;
  const int mtile = blockIdx.x;          // 0..255 (64 rows each)
  const int nt = blockIdx.y;             // 0..2  (Q, K, V weight)
  const int w = t >> 6, lane = t & 63, quad = lane >> 4, l15 = lane & 15;
  const int wm = w & 1, wn = w >> 1;

  const float* Wsel = (nt == 0) ? Wq : (nt == 1) ? Wk : Wv;

  const float* ag0 = X + (size_t)(mtile * 64 + (t >> 2)) * 1024 + (t & 3) * 8;
  const float* bg0 = Wsel + (size_t)(t >> 2) * 1024 + (t & 3) * 8;
  unsigned short* aw = &As[t * 8];       // == row(t>>2)*32 + (t&3)*8, linear in t
  unsigned short* bw = &Bs[t * 8];

  f32x4 acc[2][4] = {};

  // prologue: kt=0 A and B f32 loads in flight
  float4 a0 = *(const float4*)(ag0);
  float4 a1 = *(const float4*)(ag0 + 4);
  float4 b0 = *(const float4*)(bg0);
  float4 b1 = *(const float4*)(bg0 + 4);
  float4 b2 = *(const float4*)(bg0 + 65536);       // row +64
  float4 b3 = *(const float4*)(bg0 + 65536 + 4);

  for (int kt = 0; kt < 32; ++kt) {
    __syncthreads();                       // prior MFMA LDS reads done
    {
      union { unsigned short u[8]; uint4 v; } pa;
      pa.u[0] = f2bf(a0.x); pa.u[1] = f2bf(a0.y);
      pa.u[2] = f2bf(a0.z); pa.u[3] = f2bf(a0.w);
      pa.u[4] = f2bf(a1.x); pa.u[5] = f2bf(a1.y);
      pa.u[6] = f2bf(a1.z); pa.u[7] = f2bf(a1.w);
      *(uint4*)aw = pa.v;                  // ds_write_b128 (A row t>>2)
      union { unsigned short u[8]; uint4 v; } pb;
      pb.u[0] = f2bf(b0.x); pb.u[1] = f2bf(b0.y);
      pb.u[2] = f2bf(b0.z); pb.u[3] = f2bf(b0.w);
      pb.u[4] = f2bf(b1.x); pb.u[5] = f2bf(b1.y);
      pb.u[6] = f2bf(b1.z); pb.u[7] = f2bf(b1.w);
      *(uint4*)bw = pb.v;                  // B row t>>2
      pb.u[0] = f2bf(b2.x); pb.u[1] = f2bf(b2.y);
      pb.u[2] = f2bf(b2.z); pb.u[3] = f2bf(b2.w);
      pb.u[4] = f2bf(b3.x); pb.u[5] = f2bf(b3.y);
      pb.u[6] = f2bf(b3.z); pb.u[7] = f2bf(b3.w);
      *(uint4*)(bw + 2048) = pb.v;         // B row 64+(t>>2)
    }
    if (kt < 31) {                         // issue next-kt loads; covered by sync+MFMA
      a0 = *(const float4*)(ag0 + (kt + 1) * 32);
      a1 = *(const float4*)(ag0 + (kt + 1) * 32 + 4);
      b0 = *(const float4*)(bg0 + (kt + 1) * 32);
      b1 = *(const float4*)(bg0 + (kt + 1) * 32 + 4);
      b2 = *(const float4*)(bg0 + (kt + 1) * 32 + 65536);
      b3 = *(const float4*)(bg0 + (kt + 1) * 32 + 65536 + 4);
    }
    __syncthreads();                       // drains A/B ds_writes

    bf16x8 af[2], bfr[4];
#pragma unroll
    for (int i = 0; i < 2; ++i)
      af[i] = *(const bf16x8*)&As[(wm * 32 + i * 16 + l15) * 32 + quad * 8];
#pragma unroll
    for (int j = 0; j < 4; ++j)
      bfr[j] = *(const bf16x8*)&Bs[(wn * 64 + j * 16 + l15) * 32 + quad * 8];
#pragma unroll
    for (int i = 0; i < 2; ++i)
#pragma unroll
      for (int j = 0; j < 4; ++j)
        acc[i][j] = mfma16(af[i], bfr[j], acc[i][j]);
  }

  if (nt != 2) {
    const int m0 = mtile * 64 + wm * 32;
#pragma unroll
    for (int i = 0; i < 2; ++i)
#pragma unroll
      for (int j = 0; j < 4; ++j)
#pragma unroll
        for (int r = 0; r < 4; ++r) {
          int m = m0 + i * 16 + quad * 4 + r;
          int n = wn * 64 + j * 16 + l15;
          float v = acc[i][j][r];
          if (nt == 0) Qb[(size_t)m * 128 + n] = f2bf(v * ATTN_SCALE);
          else         Kb[(size_t)m * 128 + n] = f2bf(v);
        }
  } else {
    // transpose through LDS -> coalesced Vt writes
    // NOTE: jj loop MUST be fully unrolled (j indexes the acc register array;
    // runtime index demotes acc to scratch -> massive spill traffic).
    float* Ts = (float*)sm;                   // [64 m][17] f32 (4352 B)
    const int bb = mtile >> 6;
    const int s0 = (mtile & 63) * 64;
#pragma unroll
    for (int jj = 0; jj < 8; ++jj) {
      __syncthreads();
      if (wn == (jj >> 2)) {
        const int j = jj & 3;
#pragma unroll
        for (int i = 0; i < 2; ++i)
#pragma unroll
          for (int r = 0; r < 4; ++r)
            Ts[(wm * 32 + i * 16 + quad * 4 + r) * 17 + l15] = acc[i][j][r];
      }
      __syncthreads();
      int n2 = jj * 16 + (t >> 4);            // d index within this 16-col chunk
      int m2 = (t & 15) * 4;                  // 4 seq rows per thread
      union { unsigned short u[4]; uint2 v; } pk;
#pragma unroll
      for (int e = 0; e < 4; ++e) pk.u[e] = f2bf(Ts[(m2 + e) * 17 + (t >> 4)]);
      *(uint2*)&Vt[((size_t)(bb * 128 + n2)) * 4096 + s0 + m2] = pk.v;
    }
  }
}

// ---------------------------------------------------------------- flash attention
// v8: round-9's V-direct-from-L2 experiment, EXECUTED CORRECTLY this time.
// Round 9's 97 us regression was an in-order-vmcnt bug: K[ktn] global_load_lds
// was issued BEFORE the V register loads, so PV's wait on vfr retired the K
// prefetch too -> full L2 latency exposed every iteration (MfmaUtil 24->14,
// VGPR stuck at 84 = vfr never kept resident, +6 MB spill writes).
// Fix: (1) V reg-loads issued FIRST after the barrier, K prefetch second ->
// PV waits at vmcnt(4), K stays in flight with softmax+PV as cover;
// (2) loop-carried V pointer (vptr += 64) so the address is cheap to keep
// and vfr stays in VGPRs.
// Intent unchanged: remove V from LDS (-32 KB/block-iter of LDS traffic),
// remove the beta barrier (P is wave-private), K double-buffered, ONE
// barrier + ONE vmcnt(0) per iteration. Numerics bit-identical.
__global__ __launch_bounds__(256, 3) void k_flash(
    const unsigned short* __restrict__ Qb,   // [4][4096][128] bf16, pre-scaled
    const unsigned short* __restrict__ Kb,   // [4][4096][128] bf16
    const unsigned short* __restrict__ Vt,   // [4][128][4096] bf16
    float* __restrict__ Om,                  // [2][16384][128] f32 partials
    float* __restrict__ lp)                  // [2][16384] row sums
{
  __shared__ __align__(16) unsigned short smem[21504];   // 43008 B
  // K0 [0,8192) | K1 [8192,16384) | P [16384,21504)
  unsigned short* Psh = smem + 16384;    // per-wave [32 q][stride 40]
  float* Ob  = (float*)smem;             // epilogue overlay [64][128] f32 (over K bufs)
  float* lsh = (float*)(smem + 16384);   // epilogue overlay [64] f32 (over P)

  const int t = threadIdx.x;
  const int w = t >> 6, lane = t & 63, quad = lane >> 4, l15 = lane & 15;
  const int h = w & 1, p = w >> 1;
  // XCD-affine decode: xcd = bid & 7; pair (2b, 2b+1) = batch b; even XCD of
  // the pair gets keys 0..2047 (sp=0), odd 2048..4095. K/V ~1 MB per XCD L2.
  const int bid = blockIdx.x;            // 0..511
  const int b   = (bid & 7) >> 1;
  const int sp  = bid & 1;
  const int qt  = bid >> 3;              // 0..63

  const unsigned short* Qg = Qb + (size_t)(b * 4096 + qt * 64 + h * 32) * 128;
  const unsigned short* Kg = Kb + (size_t)b * 4096 * 128;
  const unsigned short* Vg = Vt + (size_t)b * 128 * 4096;

  bf16x8 qf[2][4];
#pragma unroll
  for (int mt = 0; mt < 2; ++mt)
#pragma unroll
    for (int kk = 0; kk < 4; ++kk)
      qf[mt][kk] = *(const bf16x8*)&Qg[(size_t)(mt * 16 + l15) * 128 + kk * 32 + quad * 8];

  f32x4 O[2][8] = {};
  f32x4 Ol[2] = {};

  // K staging map (chunk-XOR swizzled on the fetch side, as before):
  const unsigned short* kg0 = Kg + (size_t)(t >> 4) * 128 + (((t & 15) ^ ((t >> 5) & 7)) * 8);
  // V direct-read pointer: lane(l15,quad) -> d-row l15 (+dt*16),
  // key chunk (p*4+quad)*8; advances 64 keys per iteration (loop-carried).
  const unsigned short* vptr = Vg + (size_t)l15 * 4096 + (p * 4 + quad) * 8
                                  + (size_t)(sp * 32) * 64;

  const int kt0 = sp * 32;

  // prologue: K(kt0) -> K0
  {
    const unsigned short* kg = kg0 + (size_t)kt0 * 8192;
    unsigned short* kw = &smem[w * 512];
#pragma unroll
    for (int it = 0; it < 4; ++it)
      load_lds16(kg + it * 2048, kw + it * 2048);
  }

  for (int i = 0; i < 32; ++i) {
    const int cur = i & 1, nxt = cur ^ 1;
    const int ktn = (i < 31) ? (kt0 + i + 1) : kt0;   // wrap dummy on last iter

    // alpha (the ONLY barrier per iter): K[cur] resident (the 4 K loads are
    // the only outstanding vmem; V regs of iter i-1 were retired before PV).
    // Barrier also certifies all waves finished QK(i-1) -> buf[nxt] free.
    asm volatile("s_waitcnt vmcnt(0)" ::: "memory");
    asm volatile("s_barrier" ::: "memory");

    // (1) V fragments FIRST -> registers. Oldest in the vmem FIFO, so PV's
    // wait retires only these (vmcnt(4)), leaving the K prefetch in flight.
    bf16x8 vfr[8];
#pragma unroll
    for (int dt = 0; dt < 8; ++dt)
      vfr[dt] = *(const bf16x8*)&vptr[(size_t)dt * 65536];

    // (2) K[ktn] -> buf[nxt] second (has softmax+PV+next-alpha to land)
    {
      const unsigned short* kg = kg0 + (size_t)ktn * 8192;
      unsigned short* kw = &smem[nxt * 8192 + w * 512];
#pragma unroll
      for (int it = 0; it < 4; ++it)
        load_lds16(kg + it * 2048, kw + it * 2048);
    }

    // S = Q K^T on K[cur] (keys paired even/odd: lane l15 holds
    // keys p*32 + 2*l15 + ntk)
    const unsigned short* Kshc = &smem[cur * 8192];
    f32x4 sc[2][2] = {};
#pragma unroll
    for (int ntk = 0; ntk < 2; ++ntk) {
      const int row = p * 32 + 2 * l15 + ntk;
#pragma unroll
      for (int kk = 0; kk < 4; ++kk) {
        bf16x8 kf = *(const bf16x8*)&Kshc[row * 128 + (((kk * 4 + quad) ^ (l15 & 7)) * 8)];
        sc[0][ntk] = mfma16(qf[0][kk], kf, sc[0][ntk]);
        sc[1][ntk] = mfma16(qf[1][kk], kf, sc[1][ntk]);
      }
    }

    // P = exp(S) (no max shift), packed pair writes (keys 2*l15, 2*l15+1)
#pragma unroll
    for (int mt = 0; mt < 2; ++mt)
#pragma unroll
      for (int r = 0; r < 4; ++r) {
        float e0 = __expf(sc[mt][0][r]);
        float e1 = __expf(sc[mt][1][r]);
        int row = mt * 16 + quad * 4 + r;
        uint32_t pk = (uint32_t)f2bf(e0) | ((uint32_t)f2bf(e1) << 16);
        *(uint32_t*)&Psh[w * 1280 + row * 40 + 2 * l15] = pk;
      }

    // P roundtrip is wave-private: no barrier, just drain own LDS ops.
    asm volatile("s_waitcnt lgkmcnt(0)" ::: "memory");

    bf16x8 pf0 = *(const bf16x8*)&Psh[w * 1280 + l15 * 40 + quad * 8];
    bf16x8 pf1 = *(const bf16x8*)&Psh[w * 1280 + (16 + l15) * 40 + quad * 8];
    const bf16x8 one = ones_bf16();
    Ol[0] = mfma16(pf0, one, Ol[0]);     // row-sums of P (free l accumulate)
    Ol[1] = mfma16(pf1, one, Ol[1]);
#pragma unroll
    for (int dt = 0; dt < 8; ++dt) {
      O[0][dt] = mfma16(pf0, vfr[dt], O[0][dt]);
      O[1][dt] = mfma16(pf1, vfr[dt], O[1][dt]);
    }

    vptr += 64;                          // next 64-key tile
  }

  // ---- merge the two key-half partials (additive: no max state) ----
  // __syncthreads drains vmcnt(0) (wrap-dummy K prefetch lands BEFORE the
  // overlay writes below) + lgkmcnt, then barrier.
  __syncthreads();
  if (p == 1) {
#pragma unroll
    for (int mt = 0; mt < 2; ++mt)
#pragma unroll
      for (int r = 0; r < 4; ++r) {
        int row = h * 32 + mt * 16 + quad * 4 + r;
        if (l15 == 0) lsh[row] = Ol[mt][r];
#pragma unroll
        for (int dt = 0; dt < 8; ++dt)
          Ob[row * 128 + dt * 16 + l15] = O[mt][dt][r];
      }
  }
  __syncthreads();
  if (p == 0) {
    const size_t rowbase = (size_t)b * 4096 + qt * 64;
    float* Omp = Om + (size_t)sp * 2097152;
#pragma unroll
    for (int mt = 0; mt < 2; ++mt)
#pragma unroll
      for (int r = 0; r < 4; ++r) {
        int row = h * 32 + mt * 16 + quad * 4 + r;
#pragma unroll
        for (int dt = 0; dt < 8; ++dt)
          Omp[(rowbase + row) * 128 + dt * 16 + l15] =
              O[mt][dt][r] + Ob[row * 128 + dt * 16 + l15];
        if (l15 == 0)
          lp[(size_t)sp * 16384 + rowbase + row] = Ol[mt][r] + lsh[row];
      }
  }
}

// ---------------------------------------------------------------- merge key-splits
__global__ __launch_bounds__(256) void k_merge(const float* __restrict__ Om,
                                               const float* __restrict__ lp,
                                               float* __restrict__ out) {
  int i = blockIdx.x * 256 + threadIdx.x;   // float4 index, 524288 total
  int row = i >> 5;
  float inv = 1.0f / (lp[row] + lp[16384 + row]);
  float4 a = ((const float4*)Om)[i];
  float4 c = ((const float4*)Om)[524288 + i];
  float4 o;
  o.x = (a.x + c.x) * inv;
  o.y = (a.y + c.y) * inv;
  o.z = (a.z + c.z) * inv;
  o.w = (a.w + c.w) * inv;
  ((float4*)out)[i] = o;
}

// ---------------------------------------------------------------- launch
extern "C" void kernel_launch(void* const* d_in, const int* in_sizes, int n_in,
                              void* d_out, int out_size, void* d_ws, size_t ws_size,
                              hipStream_t stream) {
  const float* x  = (const float*)d_in[0];   // [4,4096,1024]
  const float* Wq = (const float*)d_in[1];   // [128,1024]
  const float* Wk = (const float*)d_in[2];
  const float* Wv = (const float*)d_in[3];
  float* out = (float*)d_out;                // [4,4096,128]

  unsigned short* ws  = (unsigned short*)d_ws;
  unsigned short* Qb  = ws;                   // 2,097,152 ush
  unsigned short* Kb  = Qb + 2097152;
  unsigned short* Vt  = Kb + 2097152;         // 2,097,152
  float* Om = (float*)(Vt + 2097152);         // 2*16384*128 f32
  float* lp = Om + 4194304;                   // 2*16384 f32

  k_proj<<<dim3(256, 3), 256, 0, stream>>>(x, Wq, Wk, Wv, Qb, Kb, Vt);
  k_flash<<<512, 256, 0, stream>>>(Qb, Kb, Vt, Om, lp);
  k_merge<<<2048, 256, 0, stream>>>(Om, lp, out);
}